// Round 8
// baseline (42.602 us; speedup 1.0000x reference)
//
#include <hip/hip_runtime.h>

#define Bn 4
#define Mn 100
#define Dn 128

// ---------------- K1: fused flag + gather -> compact per-row triples (no global atomics)
__global__ __launch_bounds__(256) void fused_kernel(
    const float* __restrict__ atten,
    const float* __restrict__ boxes,
    unsigned int* __restrict__ bcnt,
    float2* __restrict__ trip)
{
    __shared__ float abox[Mn * 18];
    __shared__ int   am[Mn];
    __shared__ int   wcnt[4], wbase[4];
    __shared__ int   nactS, nflag, ntS;
    __shared__ int   clist[256];
    __shared__ float ssum[Mn], scnt[Mn];

    const int b  = blockIdx.x >> 8;
    const int y  = blockIdx.x & 255;
    const int tx = threadIdx.x;

    if (tx == 0) { nflag = 0; ntS = 0; }
    if (tx < Mn) { ssum[tx] = 0.0f; scnt[tx] = 0.0f; }

    const float DIMS0 = 51.2f + 51.2f;
    float gy = __fadd_rn(__fmul_rn((y + 0.5f) * (1.0f / 256.0f), DIMS0), -51.2f);

    // geometry in registers (exact arithmetic of the verified rounds)
    float px[4], py[4], ex[4], ey[4];
    bool act = false;
    if (tx < Mn) {
        const float* bx = boxes + (size_t)(b * Mn + tx) * 7;
        float cx = bx[0], cy = bx[1];
        float l = bx[3], w = bx[4], yaw = bx[6];
        const float cellw = DIMS0 / 256.0f;
        float rl = fminf(fmaxf(cellw / l, 1.0f), 6.0f);
        float rw = fminf(fmaxf(cellw / w, 1.0f), 6.0f);
        float el = __fmul_rn(l, rl);
        float ew = __fmul_rn(w, rw);
        float c = cosf(yaw), s = sinf(yaw);
        const float nx[4] = {-0.5f, -0.5f, 0.5f, 0.5f};
        const float ny[4] = {-0.5f, 0.5f, 0.5f, -0.5f};
        #pragma unroll
        for (int k = 0; k < 4; k++) {
            float ox = __fmul_rn(el, nx[k]);
            float oy = __fmul_rn(ew, ny[k]);
            float rx = __fadd_rn(__fmul_rn(ox, c), __fmul_rn(oy, s));
            float ry = __fadd_rn(__fmul_rn(-ox, s), __fmul_rn(oy, c));
            px[k] = __fadd_rn(rx, cx);
            py[k] = __fadd_rn(ry, cy);
        }
        #pragma unroll
        for (int k = 0; k < 4; k++) {
            ex[k] = __fsub_rn(px[(k + 1) & 3], px[k]);
            ey[k] = __fsub_rn(py[(k + 1) & 3], py[k]);
        }
        float r = 0.5f * sqrtf(el * el + ew * ew) + 0.01f;
        act = fabsf(gy - cy) <= r;       // conservative y-band
    }

    // order-preserving compaction of y-active boxes (m order preserved)
    unsigned long long mb = __ballot(act);
    int wid = tx >> 6;
    if ((tx & 63) == 0) wcnt[wid] = __popcll(mb);
    __syncthreads();
    if (tx == 0) {
        wbase[0] = 0;
        wbase[1] = wcnt[0];
        wbase[2] = wcnt[0] + wcnt[1];
        wbase[3] = wbase[2] + wcnt[2];
        nactS    = wbase[3] + wcnt[3];
    }
    __syncthreads();
    const int nact = nactS;
    if (nact == 0) {                      // no box touches this row (block-uniform)
        if (tx == 0) bcnt[blockIdx.x] = 0;
        return;
    }
    if (act) {
        int slot = wbase[wid] + __popcll(mb & ((1ull << (tx & 63)) - 1ull));
        float* o = abox + slot * 18;
        #pragma unroll
        for (int k = 0; k < 4; k++) {
            o[k * 2] = px[k];  o[k * 2 + 1] = py[k];
            o[8 + k * 2] = ex[k]; o[8 + k * 2 + 1] = ey[k];
        }
        am[slot] = tx;
    }
    __syncthreads();

    // per-cell parity scan over the ~5 y-active boxes (broadcast LDS reads)
    float gx = __fadd_rn(__fmul_rn((tx + 0.5f) * (1.0f / 256.0f), DIMS0), -51.2f);
    int flag = -1;
    for (int j = 0; j < nact; j++) {
        const float* o = &abox[j * 18];
        bool ge = true, le = true;
        #pragma unroll
        for (int k = 0; k < 4; k++) {
            float dx = __fsub_rn(gx, o[k * 2]);
            float dy = __fsub_rn(gy, o[k * 2 + 1]);
            float cr = __fsub_rn(__fmul_rn(o[8 + k * 2], dy),
                                 __fmul_rn(o[8 + k * 2 + 1], dx));
            ge = ge && (cr >= 0.0f);
            le = le && (cr <= 0.0f);
        }
        if (ge || le) flag = (flag == -1) ? am[j] : -1;
    }
    if (flag >= 0) {
        int idx = atomicAdd(&nflag, 1);
        clist[idx] = (flag << 8) | tx;    // m (7b) | x (8b)
    }
    __syncthreads();
    const int n = nflag;
    if (n == 0) {
        if (tx == 0) bcnt[blockIdx.x] = 0;
        return;
    }

    // in-block gather: 8 lane-groups, 4-way unrolled independent loads
    const int g = tx >> 5, lane = tx & 31;
    const size_t rowbase = (size_t)blockIdx.x << 8;   // row*256 (flat cell base)
    for (int j0 = g; j0 < n; j0 += 32) {
        int   e[4];
        bool  h[4];
        float4 a[4];
        #pragma unroll
        for (int u = 0; u < 4; u++) {
            int j = j0 + u * 8;
            h[u] = j < n;
            e[u] = clist[h[u] ? j : j0];
            const float4* p = reinterpret_cast<const float4*>(
                atten + (rowbase + (e[u] & 255)) * Dn) + lane;
            a[u] = *p;                     // 4 independent loads in flight
        }
        #pragma unroll
        for (int u = 0; u < 4; u++) {
            if (!h[u]) continue;           // uniform within the 32-lane group
            float s = a[u].x + a[u].y + a[u].z + a[u].w;
            float q = a[u].x * a[u].x + a[u].y * a[u].y
                    + a[u].z * a[u].z + a[u].w * a[u].w;
            #pragma unroll
            for (int d = 16; d; d >>= 1) {
                s += __shfl_xor(s, d);
                q += __shfl_xor(q, d);
            }
            if (lane == 0) {
                float vv = (q - s * s * (1.0f / 128.0f)) * (1.0f / 127.0f);
                atomicAdd(&ssum[e[u] >> 8], vv);
                atomicAdd(&scnt[e[u] >> 8], 1.0f);
            }
        }
    }
    __syncthreads();

    // compact per-box partials: (sum, m*1024+cnt) — code exact in fp32 (< 2^24)
    if (tx < Mn && scnt[tx] > 0.0f) {
        int slot = atomicAdd(&ntS, 1);
        trip[blockIdx.x * Mn + slot] =
            make_float2(ssum[tx], (float)(tx * 1024) + scnt[tx]);
    }
    __syncthreads();
    if (tx == 0) bcnt[blockIdx.x] = (unsigned int)ntS;
}

// ---------------- K2: reduce triples -> loss (1 block, LDS bins, no global init needed)
__global__ __launch_bounds__(1024) void final_kernel(
    const unsigned int* __restrict__ bcnt,
    const float2* __restrict__ trip,
    float* __restrict__ out)
{
    __shared__ unsigned int bc[Bn * 256];
    __shared__ float bsum[Bn * Mn], bcn[Bn * Mn];
    __shared__ float sl[16], sn[16];
    const int tx = threadIdx.x;

    bc[tx] = bcnt[tx];                      // 1024 rows, 1024 threads
    for (int i = tx; i < Bn * Mn; i += 1024) { bsum[i] = 0.0f; bcn[i] = 0.0f; }
    __syncthreads();

    // flattened (row, slot) pairs: p = row*100 + i; consecutive p -> consecutive lanes
    for (int p = tx; p < 1024 * Mn; p += 1024) {
        int row = p / Mn;
        int i   = p - row * Mn;
        if (i < (int)bc[row]) {
            float2 t = trip[p];
            int code = (int)t.y;
            int m    = code >> 10;
            int bin  = (row >> 8) * Mn + m;
            atomicAdd(&bsum[bin], t.x);
            atomicAdd(&bcn[bin], (float)(code & 1023));
        }
    }
    __syncthreads();

    float loss = 0.0f, num = 0.0f;
    if (tx < Bn * Mn) {
        float c = bcn[tx];
        if (c > 0.0f) {
            loss = -(bsum[tx] / fmaxf(c, 1.0f));
            num  = 1.0f;
        }
    }
    #pragma unroll
    for (int d = 32; d; d >>= 1) {
        loss += __shfl_xor(loss, d);
        num  += __shfl_xor(num, d);
    }
    if ((tx & 63) == 0) { sl[tx >> 6] = loss; sn[tx >> 6] = num; }
    __syncthreads();
    if (tx == 0) {
        float L = 0.0f, N = 0.0f;
        #pragma unroll
        for (int i = 0; i < 16; i++) { L += sl[i]; N += sn[i]; }
        out[0] = L / fmaxf(N, 1.0f);
    }
}

extern "C" void kernel_launch(void* const* d_in, const int* in_sizes, int n_in,
                              void* d_out, int out_size, void* d_ws, size_t ws_size,
                              hipStream_t stream) {
    const float* atten = (const float*)d_in[0];
    const float* boxes = (const float*)d_in[1];
    float* out = (float*)d_out;

    // ws layout: bcnt[1024] uint | trip @ +4096 (1024*100 float2 = 800 KB)
    unsigned int* bcnt = (unsigned int*)d_ws;
    float2* trip = (float2*)((char*)d_ws + 4096);

    fused_kernel<<<Bn * 256, 256, 0, stream>>>(atten, boxes, bcnt, trip);
    final_kernel<<<1, 1024, 0, stream>>>(bcnt, trip, out);
}

// Round 9
// 19.409 us; speedup vs baseline: 2.1949x; 2.1949x over previous
//
#include <hip/hip_runtime.h>

#define Bn 4
#define Mn 100
#define Dn 128

// ---------------- K1: flags -> deterministic per-row cell lists (verbatim R5, verified)
__global__ __launch_bounds__(256) void flag_kernel(
    const float* __restrict__ boxes,
    unsigned int* __restrict__ rowcnt,
    unsigned int* __restrict__ cells,
    float* __restrict__ gz)            // gsum|gcnt region: 2*Bn*Mn floats
{
    __shared__ float abox[Mn * 18];
    __shared__ int   am[Mn];
    __shared__ int   wcnt[4], wbase[4];
    __shared__ int   nactS, nflag;
    __shared__ int   clist[256];

    const int b  = blockIdx.x >> 8;
    const int y  = blockIdx.x & 255;
    const int tx = threadIdx.x;

    // zero the accumulator region (visible to gather via kernel boundary)
    if (blockIdx.x < 2 * Bn * Mn && tx == 0) gz[blockIdx.x] = 0.0f;
    if (tx == 0) nflag = 0;

    const float DIMS0 = 51.2f + 51.2f;
    float gy = __fadd_rn(__fmul_rn((y + 0.5f) * (1.0f / 256.0f), DIMS0), -51.2f);

    // geometry in registers (exact arithmetic of the verified rounds)
    float px[4], py[4], ex[4], ey[4];
    bool act = false;
    if (tx < Mn) {
        const float* bx = boxes + (size_t)(b * Mn + tx) * 7;
        float cx = bx[0], cy = bx[1];
        float l = bx[3], w = bx[4], yaw = bx[6];
        const float cellw = DIMS0 / 256.0f;
        float rl = fminf(fmaxf(cellw / l, 1.0f), 6.0f);
        float rw = fminf(fmaxf(cellw / w, 1.0f), 6.0f);
        float el = __fmul_rn(l, rl);
        float ew = __fmul_rn(w, rw);
        float c = cosf(yaw), s = sinf(yaw);
        const float nx[4] = {-0.5f, -0.5f, 0.5f, 0.5f};
        const float ny[4] = {-0.5f, 0.5f, 0.5f, -0.5f};
        #pragma unroll
        for (int k = 0; k < 4; k++) {
            float ox = __fmul_rn(el, nx[k]);
            float oy = __fmul_rn(ew, ny[k]);
            float rx = __fadd_rn(__fmul_rn(ox, c), __fmul_rn(oy, s));
            float ry = __fadd_rn(__fmul_rn(-ox, s), __fmul_rn(oy, c));
            px[k] = __fadd_rn(rx, cx);
            py[k] = __fadd_rn(ry, cy);
        }
        #pragma unroll
        for (int k = 0; k < 4; k++) {
            ex[k] = __fsub_rn(px[(k + 1) & 3], px[k]);
            ey[k] = __fsub_rn(py[(k + 1) & 3], py[k]);
        }
        float r = 0.5f * sqrtf(el * el + ew * ew) + 0.01f;
        act = fabsf(gy - cy) <= r;       // conservative y-band
    }

    // order-preserving compaction of y-active boxes (m order preserved)
    unsigned long long mb = __ballot(act);
    int wid = tx >> 6;
    if ((tx & 63) == 0) wcnt[wid] = __popcll(mb);
    __syncthreads();
    if (tx == 0) {
        wbase[0] = 0;
        wbase[1] = wcnt[0];
        wbase[2] = wcnt[0] + wcnt[1];
        wbase[3] = wbase[2] + wcnt[2];
        nactS    = wbase[3] + wcnt[3];
    }
    __syncthreads();
    const int nact = nactS;
    if (nact == 0) {                      // no box touches this row
        if (tx == 0) rowcnt[blockIdx.x] = 0;
        return;
    }
    if (act) {
        int slot = wbase[wid] + __popcll(mb & ((1ull << (tx & 63)) - 1ull));
        float* o = abox + slot * 18;
        #pragma unroll
        for (int k = 0; k < 4; k++) {
            o[k * 2] = px[k];  o[k * 2 + 1] = py[k];
            o[8 + k * 2] = ex[k]; o[8 + k * 2 + 1] = ey[k];
        }
        am[slot] = tx;
    }
    __syncthreads();

    // per-cell parity scan over the ~5 y-active boxes (broadcast LDS reads)
    float gx = __fadd_rn(__fmul_rn((tx + 0.5f) * (1.0f / 256.0f), DIMS0), -51.2f);
    int flag = -1;
    for (int j = 0; j < nact; j++) {
        const float* o = &abox[j * 18];
        bool ge = true, le = true;
        #pragma unroll
        for (int k = 0; k < 4; k++) {
            float dx = __fsub_rn(gx, o[k * 2]);
            float dy = __fsub_rn(gy, o[k * 2 + 1]);
            float cr = __fsub_rn(__fmul_rn(o[8 + k * 2], dy),
                                 __fmul_rn(o[8 + k * 2 + 1], dx));
            ge = ge && (cr >= 0.0f);
            le = le && (cr <= 0.0f);
        }
        if (ge || le) flag = (flag == -1) ? am[j] : -1;
    }

    if (flag >= 0) {
        int idx = atomicAdd(&nflag, 1);
        clist[idx] = (flag << 8) | tx;    // m (7b) | x (8b)
    }
    __syncthreads();
    if (tx == 0) rowcnt[blockIdx.x] = nflag;
    for (int i = tx; i < nflag; i += 256)
        cells[(blockIdx.x << 8) + i] = clist[i];
}

// ---------------- K2: sparse variance gather — 16-lane groups (float8/lane),
//                     2 blocks/row (32 groups) + 2-way row unroll
__global__ __launch_bounds__(256) void gather_kernel(
    const float* __restrict__ atten,
    const unsigned int* __restrict__ rowcnt,
    const unsigned int* __restrict__ cells,
    float* __restrict__ gsum, float* __restrict__ gcnt)
{
    __shared__ float ssum[Mn], scnt[Mn];
    const int tx   = threadIdx.x;
    const int row  = blockIdx.x >> 1;        // 0..1023 = b*256+y
    const int half = blockIdx.x & 1;
    const int b    = row >> 8;
    const unsigned int n = rowcnt[row];

    if (tx < Mn) { ssum[tx] = 0.0f; scnt[tx] = 0.0f; }
    if (n == 0) return;                      // block-uniform
    __syncthreads();

    const int g    = (half << 4) + (tx >> 4);   // 0..31 groups across the row
    const int lane = tx & 15;
    const unsigned int base = (unsigned int)row << 8;
    const size_t rowbase = (size_t)base;

    for (unsigned int j = g; j < n; j += 64) {
        unsigned int e0 = cells[base + j];
        unsigned int j1 = j + 32;
        bool h1 = j1 < n;
        unsigned int e1 = h1 ? cells[base + j1] : e0;
        const float4* p0 = reinterpret_cast<const float4*>(
            atten + (rowbase + (e0 & 255)) * Dn);
        const float4* p1 = reinterpret_cast<const float4*>(
            atten + (rowbase + (e1 & 255)) * Dn);
        float4 a0 = p0[lane];
        float4 b0 = p0[lane + 16];
        float4 a1 = p1[lane];
        float4 b1 = p1[lane + 16];          // 4 independent loads in flight

        float s0 = (a0.x + a0.y + a0.z + a0.w) + (b0.x + b0.y + b0.z + b0.w);
        float q0 = (a0.x * a0.x + a0.y * a0.y + a0.z * a0.z + a0.w * a0.w)
                 + (b0.x * b0.x + b0.y * b0.y + b0.z * b0.z + b0.w * b0.w);
        float s1 = (a1.x + a1.y + a1.z + a1.w) + (b1.x + b1.y + b1.z + b1.w);
        float q1 = (a1.x * a1.x + a1.y * a1.y + a1.z * a1.z + a1.w * a1.w)
                 + (b1.x * b1.x + b1.y * b1.y + b1.z * b1.z + b1.w * b1.w);
        #pragma unroll
        for (int d = 8; d; d >>= 1) {
            s0 += __shfl_xor(s0, d);
            q0 += __shfl_xor(q0, d);
            s1 += __shfl_xor(s1, d);
            q1 += __shfl_xor(q1, d);
        }
        if (lane == 0) {
            float v0 = (q0 - s0 * s0 * (1.0f / 128.0f)) * (1.0f / 127.0f);
            atomicAdd(&ssum[e0 >> 8], v0);
            atomicAdd(&scnt[e0 >> 8], 1.0f);
            if (h1) {
                float v1 = (q1 - s1 * s1 * (1.0f / 128.0f)) * (1.0f / 127.0f);
                atomicAdd(&ssum[e1 >> 8], v1);
                atomicAdd(&scnt[e1 >> 8], 1.0f);
            }
        }
    }
    __syncthreads();
    if (tx < Mn && scnt[tx] > 0.0f) {
        atomicAdd(&gsum[b * Mn + tx], ssum[tx]);
        atomicAdd(&gcnt[b * Mn + tx], scnt[tx]);
    }
}

// ---------------- K3: finalize scalar loss (1 block; verbatim R5, verified)
__global__ __launch_bounds__(512) void final_kernel(const float* __restrict__ gsum,
                                                    const float* __restrict__ gcnt,
                                                    float* __restrict__ out) {
    __shared__ float sl[8], sn[8];
    int t = threadIdx.x;
    float loss = 0.0f, num = 0.0f;
    if (t < Bn * Mn) {
        float c = gcnt[t];
        if (c > 0.0f) {
            loss = -(gsum[t] / fmaxf(c, 1.0f));
            num = 1.0f;
        }
    }
    #pragma unroll
    for (int m = 32; m; m >>= 1) {
        loss += __shfl_xor(loss, m);
        num  += __shfl_xor(num, m);
    }
    if ((t & 63) == 0) { sl[t >> 6] = loss; sn[t >> 6] = num; }
    __syncthreads();
    if (t == 0) {
        float L = 0.0f, N = 0.0f;
        #pragma unroll
        for (int i = 0; i < 8; i++) { L += sl[i]; N += sn[i]; }
        out[0] = L / fmaxf(N, 1.0f);
    }
}

extern "C" void kernel_launch(void* const* d_in, const int* in_sizes, int n_in,
                              void* d_out, int out_size, void* d_ws, size_t ws_size,
                              hipStream_t stream) {
    const float* atten = (const float*)d_in[0];
    const float* boxes = (const float*)d_in[1];
    float* out = (float*)d_out;

    // ws layout: gsum[400] | gcnt[400] | rowcnt[1024] @+3200 | cells @+8192 (1 MB)
    float* gsum = (float*)d_ws;
    float* gcnt = gsum + Bn * Mn;
    unsigned int* rowcnt = (unsigned int*)((char*)d_ws + 3200);
    unsigned int* cells  = (unsigned int*)((char*)d_ws + 8192);

    flag_kernel<<<Bn * 256, 256, 0, stream>>>(boxes, rowcnt, cells, gsum);
    gather_kernel<<<2 * Bn * 256, 256, 0, stream>>>(atten, rowcnt, cells, gsum, gcnt);
    final_kernel<<<1, 512, 0, stream>>>(gsum, gcnt, out);
}